// Round 8
// baseline (71.839 us; speedup 1.0000x reference)
//
#include <hip/hip_runtime.h>
#include <hip/hip_bf16.h>
#include <math.h>

// Problem constants (from reference)
#define R_CHK   144
#define N_VAR   576
#define BATCH   512
#define ITERS   3
#define NLEV    16
#define ROW_DEG 15
#define N_EDGE  (R_CHK * ROW_DEG)    // 2160
#define NWORDS  9                    // 576 / 64
#define DEG_PAD 16                   // padded max column degree
#define NPAIR   (R_CHK * NWORDS)     // 1296 (row,word) ballot pairs
#define CH      27                   // phase-0 chunk (324 = 12 * 27)

// ---------------------------------------------------------------------------
// Single fused kernel: one block per batch element. Each block builds the
// sparse index from H locally (H is L2-resident; build is ~2-3 us and fully
// parallel across 512 blocks), then runs the validated round-5 decode body.
// ---------------------------------------------------------------------------
__launch_bounds__(256)
__global__ void fused_decode(const float* __restrict__ r,
                             const float* __restrict__ alpha,
                             const float* __restrict__ beta,
                             const float* __restrict__ eta,
                             const float* __restrict__ qkg,
                             const float* __restrict__ H,
                             float* __restrict__ out) {
    __shared__ unsigned long long sb[NPAIR];            // 10368 B bitmask
    __shared__ int spref[NPAIR];                        //  5184 B prefix popc
    __shared__ unsigned short scr[256][DEG_PAD];        //  8192 B per-thread scratch
    __shared__ float sE[N_EDGE + 1];                    //  8644 B (+ zero pad slot)
    __shared__ float st[N_VAR];                         //  2304 B

    const int b    = blockIdx.x;
    const int t    = threadIdx.x;
    const int w    = t >> 6;
    const int lane = t & 63;

    // Issue input loads early (they drain while the build runs).
    const float rv0 = r[b * N_VAR + t];
    const float rv1 = r[b * N_VAR + t + 256];
    const float rv2 = (t < 64) ? r[b * N_VAR + t + 512] : 0.0f;

    const float qv = qkg[t & 15];        // lane L holds qk[L&15] -> __shfl lookup
    float bnd[NLEV - 1];
#pragma unroll
    for (int j = 0; j < NLEV - 1; ++j) bnd[j] = 0.5f * (qkg[j] + qkg[j + 1]);
    auto QI = [&](float y) -> int {      // exact searchsorted(side=left) index
        int idx = 0;
#pragma unroll
        for (int j = 0; j < NLEV - 1; ++j) idx += (y > bnd[j]) ? 1 : 0;
        return idx;
    };

    float av[ITERS], bv[ITERS], ev[ITERS];
#pragma unroll
    for (int i = 0; i < ITERS; ++i) { av[i] = alpha[i]; bv[i] = beta[i]; ev[i] = eta[i]; }

    // ---------------- build phase 0: H -> 144x9 u64 bitmask ----------------
    // wave w handles pairs q = w + 4*i (i < 324); loads chunked for latency.
    for (int c0 = 0; c0 < 324; c0 += CH) {
        float h[CH];
#pragma unroll
        for (int j = 0; j < CH; ++j) {
            int q = w + 4 * (c0 + j);
            h[j] = H[(q / NWORDS) * N_VAR + (q % NWORDS) * 64 + lane];
        }
#pragma unroll
        for (int j = 0; j < CH; ++j) {
            int q = w + 4 * (c0 + j);
            unsigned long long m = __ballot(h[j] > 0.5f);
            if (lane == 0) sb[q] = m;
        }
    }
    __syncthreads();

    // ---------------- build phase 1: row lists + prefix popcounts ----------
    const bool isrow = (t < R_CHK);
    int cols[ROW_DEG];
    if (isrow) {
        int p = 0;
#pragma unroll
        for (int s = 0; s < NWORDS; ++s) {
            spref[t * NWORDS + s] = p;
            p += __popcll(sb[t * NWORDS + s]);
        }
        // static-index extraction of the 15 set bits (ascending columns)
        int widx = 0;
        unsigned long long m = sb[t * NWORDS];
#pragma unroll
        for (int j = 0; j < ROW_DEG; ++j) {
            while (m == 0ull) { ++widx; m = sb[t * NWORDS + widx]; }
            cols[j] = widx * 64 + (__ffsll((long long)m) - 1);
            m &= m - 1;
        }
    }
    __syncthreads();

    // ---------------- build phase 2: column tables (regs, static index) ----
    // Thread t owns columns t, t+256, t+512(<64). Runtime insert goes through
    // a private LDS scratch row, then reads back with static indices.
    int ce0[DEG_PAD], ce1[DEG_PAD], ce2[DEG_PAD];
#pragma unroll
    for (int cc = 0; cc < 3; ++cc) {
        const int c = t + 256 * cc;
        if (c < N_VAR) {
            const int wq  = c >> 6;            // wave-uniform -> LDS broadcast reads
            const int bit = c & 63;
            const unsigned long long vmask = 1ull << bit;
            const unsigned long long lowm  = vmask - 1ull;
            int n = 0;
            for (int i0 = 0; i0 < R_CHK; i0 += 16) {
                unsigned long long mw[16];
                int pf[16];
#pragma unroll
                for (int j = 0; j < 16; ++j) {
                    mw[j] = sb[(i0 + j) * NWORDS + wq];
                    pf[j] = spref[(i0 + j) * NWORDS + wq];
                }
#pragma unroll
                for (int j = 0; j < 16; ++j) {
                    if (mw[j] & vmask) {
                        int rank = pf[j] + __popcll(mw[j] & lowm);
                        if (n < DEG_PAD)
                            scr[t][n] = (unsigned short)((i0 + j) * ROW_DEG + rank);
                        ++n;
                    }
                }
            }
            for (int j = (n < DEG_PAD ? n : DEG_PAD); j < DEG_PAD; ++j)
                scr[t][j] = (unsigned short)N_EDGE;    // pad -> sE zero slot
            // read back (same thread wrote it; no barrier needed)
            if (cc == 0) {
#pragma unroll
                for (int j = 0; j < DEG_PAD; ++j) ce0[j] = scr[t][j];
            } else if (cc == 1) {
#pragma unroll
                for (int j = 0; j < DEG_PAD; ++j) ce1[j] = scr[t][j];
            } else {
#pragma unroll
                for (int j = 0; j < DEG_PAD; ++j) ce2[j] = scr[t][j];
            }
        }
    }

    // ---------------- decode init ------------------------------------------
    st[t] = rv0;
    st[t + 256] = rv1;
    if (t < 64) st[t + 512] = rv2;
    if (t == 0) sE[N_EDGE] = 0.0f;
    __syncthreads();

    const float q0 = __shfl(qv, QI(0.0f));   // quantize(exact 0), hoisted

    float M[ROW_DEG], Eq[ROW_DEG];
    if (isrow) {
#pragma unroll
        for (int k = 0; k < ROW_DEG; ++k) M[k] = st[cols[k]];   // M = H*r
    }

#pragma unroll
    for (int it = 0; it < ITERS; ++it) {
        const float a = av[it], bta = bv[it], et = ev[it];

        if (isrow) {
            // ---- fused M-update from previous iteration (eta_{it-1}) -----
            if (it > 0) {
                const float etp = ev[it - 1];
#pragma unroll
                for (int k = 0; k < ROW_DEG; ++k) {
                    float x = st[cols[k]] - Eq[k];    // (r+col) - E
                    M[k] = __shfl(qv, QI(etp * x));
                }
            }

            // ---- signs + tree sign-product (order-exact: +-1/0) ----------
            float sg[ROW_DEG];
#pragma unroll
            for (int k = 0; k < ROW_DEG; ++k)
                sg[k] = (M[k] > 0.0f) ? 1.0f : ((M[k] < 0.0f) ? -1.0f : 0.0f);
            float t0 = sg[0] * sg[1],  t1 = sg[2] * sg[3];
            float t2 = sg[4] * sg[5],  t3 = sg[6] * sg[7];
            float t4 = sg[8] * sg[9],  t5 = sg[10] * sg[11];
            float t6 = sg[12] * sg[13], t7 = sg[14];
            float u0 = t0 * t1, u1 = t2 * t3, u2 = t4 * t5, u3 = t6 * t7;
            const float prod = (u0 * u1) * (u2 * u3);

            // ---- tree min2 over |M| (exact multiset selection) -----------
            float a1[8], a2[8];
#pragma unroll
            for (int k = 0; k < 7; ++k) {
                float x = fabsf(M[2 * k]), y = fabsf(M[2 * k + 1]);
                a1[k] = fminf(x, y); a2[k] = fmaxf(x, y);
            }
            a1[7] = fabsf(M[14]); a2[7] = INFINITY;
#pragma unroll
            for (int s = 4; s >= 1; s >>= 1) {
#pragma unroll
                for (int k = 0; k < 4; ++k) {
                    if (k < s) {
                        float lo = fminf(a1[k], a1[k + s]);
                        float hi = fminf(fmaxf(a1[k], a1[k + s]), fminf(a2[k], a2[k + s]));
                        a1[k] = lo; a2[k] = hi;
                    }
                }
            }
            const float m1 = a1[0], m2 = a2[0];

            // ---- E candidates + per-edge select + quantize ---------------
            const float ap = a * prod;
            const float g1 = fmaxf(m1 - bta, 0.0f);
            const float g2 = fmaxf(m2 - bta, 0.0f);
            const float y1 = et * (ap * g1);
            const float y2 = et * (ap * g2);
            const float c1p = __shfl(qv, QI(y1)), c1m = __shfl(qv, QI(-y1));
            const float c2p = __shfl(qv, QI(y2)), c2m = __shfl(qv, QI(-y2));
#pragma unroll
            for (int k = 0; k < ROW_DEG; ++k) {
                const bool ismin = (fabsf(M[k]) == m1);    // -> mexcl = m2
                float cp = ismin ? c2p : c1p;
                float cm = ismin ? c2m : c1m;
                float q = (sg[k] > 0.0f) ? cp : cm;
                q = (sg[k] == 0.0f) ? q0 : q;
                Eq[k] = q;
                sE[t * ROW_DEG + k] = q;
            }
        }
        __syncthreads();

        // ---- column phase: fixed-degree sums (ascending row order) -------
        {
            float s0 = 0.0f, s1 = 0.0f, s2 = 0.0f;
#pragma unroll
            for (int j = 0; j < DEG_PAD; ++j) s0 += sE[ce0[j]];
#pragma unroll
            for (int j = 0; j < DEG_PAD; ++j) s1 += sE[ce1[j]];
            if (t < 64) {
#pragma unroll
                for (int j = 0; j < DEG_PAD; ++j) s2 += sE[ce2[j]];
            }
            float w0 = rv0 + s0;
            float w1 = rv1 + s1;
            st[t] = w0;
            st[t + 256] = w1;
            float w2 = 0.0f;
            if (t < 64) { w2 = rv2 + s2; st[t + 512] = w2; }
            if (it == ITERS - 1) {
                out[b * N_VAR + t] = w0;
                out[b * N_VAR + t + 256] = w1;
                if (t < 64) out[b * N_VAR + t + 512] = w2;
            }
        }
        if (it < ITERS - 1) __syncthreads();
    }
}

// ---------------------------------------------------------------------------
extern "C" void kernel_launch(void* const* d_in, const int* in_sizes, int n_in,
                              void* d_out, int out_size, void* d_ws, size_t ws_size,
                              hipStream_t stream) {
    const float* r     = (const float*)d_in[0];
    const float* alpha = (const float*)d_in[1];
    const float* beta  = (const float*)d_in[2];
    const float* eta   = (const float*)d_in[3];
    const float* qk    = (const float*)d_in[4];
    const float* H     = (const float*)d_in[5];
    float* out = (float*)d_out;

    fused_decode<<<BATCH, 256, 0, stream>>>(r, alpha, beta, eta, qk, H, out);
}

// Round 9
// 41.828 us; speedup vs baseline: 1.7175x; 1.7175x over previous
//
#include <hip/hip_runtime.h>
#include <hip/hip_bf16.h>
#include <math.h>

// Problem constants (from reference)
#define R_CHK   144
#define N_VAR   576
#define BATCH   512
#define ITERS   3
#define NLEV    16
#define ROW_DEG 15
#define N_EDGE  (R_CHK * ROW_DEG)    // 2160
#define NWORDS  9                    // 576 / 64
#define DEG_PAD 16                   // padded max column degree
#define NTHR    576                  // k12 threads (9 waves)

// ---------------------------------------------------------------------------
// K12: fused index build (one 576-thread block, runs once, ~5 us).
//  - ballot-compress H into a 144x9 u64 bitmask in LDS
//  - per-row edge column lists (ascending cols)
//  - per-column u16 edge-id table (ascending rows), ids = row*15 + rank,
//    padded with N_EDGE (decode's sE zero slot)
// ---------------------------------------------------------------------------
__launch_bounds__(NTHR)
__global__ void k12_index(const float* __restrict__ H,
                          int* __restrict__ edge_cols,
                          unsigned short* __restrict__ col_pack) {
    __shared__ unsigned long long sb[R_CHK * NWORDS];   // 10368 B
    __shared__ int spref[R_CHK * NWORDS];               //  5184 B

    const int t    = threadIdx.x;
    const int w    = t >> 6;
    const int lane = t & 63;

    // Phase 0: bitmask via ballots, 4 rows' loads in flight per chunk.
    for (int j0 = 0; j0 < 16; j0 += 4) {
        float h[4][NWORDS];
#pragma unroll
        for (int jj = 0; jj < 4; ++jj)
#pragma unroll
            for (int s = 0; s < NWORDS; ++s)
                h[jj][s] = H[(16 * w + j0 + jj) * N_VAR + s * 64 + lane];
#pragma unroll
        for (int jj = 0; jj < 4; ++jj)
#pragma unroll
            for (int s = 0; s < NWORDS; ++s) {
                unsigned long long m = __ballot(h[jj][s] > 0.5f);
                if (lane == s) sb[(16 * w + j0 + jj) * NWORDS + s] = m;
            }
    }
    __syncthreads();

    // Phase 1: per-row extraction + word-prefix popcounts.
    if (t < R_CHK) {
        int k = 0, p = 0;
#pragma unroll
        for (int s = 0; s < NWORDS; ++s) {
            unsigned long long m = sb[t * NWORDS + s];
            spref[t * NWORDS + s] = p;
            p += __popcll(m);
            while (m) {
                int bpos = __ffsll((long long)m) - 1;
                if (k < ROW_DEG) edge_cols[t * ROW_DEG + k] = s * 64 + bpos;
                ++k;
                m &= m - 1;
            }
        }
    }
    __syncthreads();

    // Phase 2: per-column table (ascending row order), u16 edge ids.
    {
        const int wq  = t >> 6;
        const int bit = t & 63;
        const unsigned long long vmask   = 1ull << bit;
        const unsigned long long lowmask = vmask - 1ull;
        int n = 0;
        for (int i0 = 0; i0 < R_CHK; i0 += 16) {
            unsigned long long mw[16];
            int pf[16];
#pragma unroll
            for (int j = 0; j < 16; ++j) {
                mw[j] = sb[(i0 + j) * NWORDS + wq];
                pf[j] = spref[(i0 + j) * NWORDS + wq];
            }
#pragma unroll
            for (int j = 0; j < 16; ++j) {
                if (mw[j] & vmask) {
                    int rank = pf[j] + __popcll(mw[j] & lowmask);
                    if (n < DEG_PAD)
                        col_pack[t * DEG_PAD + n] =
                            (unsigned short)((i0 + j) * ROW_DEG + rank);
                    ++n;
                }
            }
        }
        for (int j = (n < DEG_PAD ? n : DEG_PAD); j < DEG_PAD; ++j)
            col_pack[t * DEG_PAD + j] = (unsigned short)N_EDGE;  // pad -> zero slot
    }
}

// ---------------------------------------------------------------------------
// Decode: one batch per 256-thread block. Thread-per-row (15 reg messages),
// u16-packed register column tables, pure-VALU quantizer (no cross-lane ops).
// ---------------------------------------------------------------------------
__launch_bounds__(256, 2)
__global__ void decode_kernel(const float* __restrict__ r,
                              const float* __restrict__ alpha,
                              const float* __restrict__ beta,
                              const float* __restrict__ eta,
                              const float* __restrict__ qkg,
                              const int* __restrict__ edge_cols,
                              const unsigned short* __restrict__ col_pack,
                              float* __restrict__ out) {
    __shared__ float sE[N_EDGE + 1];   // +1: zero slot for padded column reads
    __shared__ float st[N_VAR];        // r (init), then r + colsum

    const int b = blockIdx.x;
    const int t = threadIdx.x;

    // Input loads issued early.
    const float rv0 = r[b * N_VAR + t];
    const float rv1 = r[b * N_VAR + t + 256];
    const float rv2 = (t < 64) ? r[b * N_VAR + t + 512] : 0.0f;

    // Quantizer fully in registers: exact searchsorted(side=left) semantics,
    // value produced by a monotone cndmask chain (same predicate as jnp).
    float qk[NLEV], bnd[NLEV - 1];
#pragma unroll
    for (int j = 0; j < NLEV; ++j) qk[j] = qkg[j];
#pragma unroll
    for (int j = 0; j < NLEV - 1; ++j) bnd[j] = 0.5f * (qk[j] + qk[j + 1]);
    auto QZ = [&](float y) -> float {
        float q = qk[0];
#pragma unroll
        for (int j = 0; j < NLEV - 1; ++j) q = (y > bnd[j]) ? qk[j + 1] : q;
        return q;
    };
    const float q0 = QZ(0.0f);   // quantize(exact 0), hoisted

    float av[ITERS], bv[ITERS], ev[ITERS];
#pragma unroll
    for (int i = 0; i < ITERS; ++i) { av[i] = alpha[i]; bv[i] = beta[i]; ev[i] = eta[i]; }

    // u16-packed register column tables (2 ids per u32; 24 VGPRs total).
    unsigned pa[8], pb[8], pc[8];
    {
        const uint4* base = (const uint4*)col_pack;
        uint4 a0 = base[t * 2], a1 = base[t * 2 + 1];
        pa[0] = a0.x; pa[1] = a0.y; pa[2] = a0.z; pa[3] = a0.w;
        pa[4] = a1.x; pa[5] = a1.y; pa[6] = a1.z; pa[7] = a1.w;
        uint4 b0 = base[(t + 256) * 2], b1 = base[(t + 256) * 2 + 1];
        pb[0] = b0.x; pb[1] = b0.y; pb[2] = b0.z; pb[3] = b0.w;
        pb[4] = b1.x; pb[5] = b1.y; pb[6] = b1.z; pb[7] = b1.w;
        if (t < 64) {
            uint4 c0 = base[(t + 512) * 2], c1 = base[(t + 512) * 2 + 1];
            pc[0] = c0.x; pc[1] = c0.y; pc[2] = c0.z; pc[3] = c0.w;
            pc[4] = c1.x; pc[5] = c1.y; pc[6] = c1.z; pc[7] = c1.w;
        }
    }

    const bool isrow = (t < R_CHK);
    int cols[ROW_DEG];
    if (isrow) {
#pragma unroll
        for (int k = 0; k < ROW_DEG; ++k) cols[k] = edge_cols[t * ROW_DEG + k];
    }

    st[t] = rv0;
    st[t + 256] = rv1;
    if (t < 64) st[t + 512] = rv2;
    if (t == 0) sE[N_EDGE] = 0.0f;
    __syncthreads();

    float M[ROW_DEG], Eq[ROW_DEG];
    if (isrow) {
#pragma unroll
        for (int k = 0; k < ROW_DEG; ++k) M[k] = st[cols[k]];   // M = H*r
    }

#pragma unroll
    for (int it = 0; it < ITERS; ++it) {
        const float a = av[it], bta = bv[it], et = ev[it];

        if (isrow) {
            // ---- fused M-update from previous iteration (eta_{it-1}) -----
            if (it > 0) {
                const float etp = ev[it - 1];
#pragma unroll
                for (int k = 0; k < ROW_DEG; ++k) {
                    float x = st[cols[k]] - Eq[k];    // (r+col) - E
                    M[k] = QZ(etp * x);
                }
            }

            // ---- signs + tree sign-product (order-exact: +-1/0) ----------
            float sg[ROW_DEG];
#pragma unroll
            for (int k = 0; k < ROW_DEG; ++k)
                sg[k] = (M[k] > 0.0f) ? 1.0f : ((M[k] < 0.0f) ? -1.0f : 0.0f);
            float t0 = sg[0] * sg[1],  t1 = sg[2] * sg[3];
            float t2 = sg[4] * sg[5],  t3 = sg[6] * sg[7];
            float t4 = sg[8] * sg[9],  t5 = sg[10] * sg[11];
            float t6 = sg[12] * sg[13], t7 = sg[14];
            float u0 = t0 * t1, u1 = t2 * t3, u2 = t4 * t5, u3 = t6 * t7;
            const float prod = (u0 * u1) * (u2 * u3);

            // ---- tree min2 over |M| (exact multiset selection) -----------
            float a1[8], a2[8];
#pragma unroll
            for (int k = 0; k < 7; ++k) {
                float x = fabsf(M[2 * k]), y = fabsf(M[2 * k + 1]);
                a1[k] = fminf(x, y); a2[k] = fmaxf(x, y);
            }
            a1[7] = fabsf(M[14]); a2[7] = INFINITY;
#pragma unroll
            for (int s = 4; s >= 1; s >>= 1) {
#pragma unroll
                for (int k = 0; k < 4; ++k) {
                    if (k < s) {
                        float lo = fminf(a1[k], a1[k + s]);
                        float hi = fminf(fmaxf(a1[k], a1[k + s]), fminf(a2[k], a2[k + s]));
                        a1[k] = lo; a2[k] = hi;
                    }
                }
            }
            const float m1 = a1[0], m2 = a2[0];

            // ---- E candidates + per-edge select (bit-exact vs reference) -
            const float ap = a * prod;
            const float g1 = fmaxf(m1 - bta, 0.0f);
            const float g2 = fmaxf(m2 - bta, 0.0f);
            const float y1 = et * (ap * g1);
            const float y2 = et * (ap * g2);
            const float c1p = QZ(y1), c1m = QZ(-y1);
            const float c2p = QZ(y2), c2m = QZ(-y2);
#pragma unroll
            for (int k = 0; k < ROW_DEG; ++k) {
                const bool ismin = (fabsf(M[k]) == m1);    // -> mexcl = m2
                float cp = ismin ? c2p : c1p;
                float cm = ismin ? c2m : c1m;
                float q = (sg[k] > 0.0f) ? cp : cm;
                q = (sg[k] == 0.0f) ? q0 : q;
                Eq[k] = q;
                sE[t * ROW_DEG + k] = q;
            }
        }
        __syncthreads();

        // ---- column phase: fixed-degree sums (ascending row order) -------
        {
            float s0 = 0.0f, s1 = 0.0f, s2 = 0.0f;
#pragma unroll
            for (int j = 0; j < DEG_PAD; ++j) {
                int id = (pa[j >> 1] >> (16 * (j & 1))) & 0xffff;
                s0 += sE[id];
            }
#pragma unroll
            for (int j = 0; j < DEG_PAD; ++j) {
                int id = (pb[j >> 1] >> (16 * (j & 1))) & 0xffff;
                s1 += sE[id];
            }
            if (t < 64) {
#pragma unroll
                for (int j = 0; j < DEG_PAD; ++j) {
                    int id = (pc[j >> 1] >> (16 * (j & 1))) & 0xffff;
                    s2 += sE[id];
                }
            }
            float w0 = rv0 + s0;
            float w1 = rv1 + s1;
            st[t] = w0;
            st[t + 256] = w1;
            float w2 = 0.0f;
            if (t < 64) { w2 = rv2 + s2; st[t + 512] = w2; }
            if (it == ITERS - 1) {
                out[b * N_VAR + t] = w0;
                out[b * N_VAR + t + 256] = w1;
                if (t < 64) out[b * N_VAR + t + 512] = w2;
            }
        }
        if (it < ITERS - 1) __syncthreads();
    }
}

// ---------------------------------------------------------------------------
extern "C" void kernel_launch(void* const* d_in, const int* in_sizes, int n_in,
                              void* d_out, int out_size, void* d_ws, size_t ws_size,
                              hipStream_t stream) {
    const float* r     = (const float*)d_in[0];
    const float* alpha = (const float*)d_in[1];
    const float* beta  = (const float*)d_in[2];
    const float* eta   = (const float*)d_in[3];
    const float* qk    = (const float*)d_in[4];
    const float* H     = (const float*)d_in[5];
    float* out = (float*)d_out;

    // workspace layout
    int* edge_cols = (int*)d_ws;                                      // 2160 ints (8640 B, 16B-aligned)
    unsigned short* col_pack = (unsigned short*)(edge_cols + N_EDGE); // 576*16 u16

    k12_index<<<1, NTHR, 0, stream>>>(H, edge_cols, col_pack);
    decode_kernel<<<BATCH, 256, 0, stream>>>(r, alpha, beta, eta, qk,
                                             edge_cols, col_pack, out);
}